// Round 10
// baseline (245.809 us; speedup 1.0000x reference)
//
#include <hip/hip_runtime.h>

#define NPTS 65536
#define EPSV 1e-5f

typedef unsigned int uint_t;
typedef unsigned short ushort_t;
typedef __attribute__((ext_vector_type(8))) short short8;
typedef __attribute__((ext_vector_type(4))) float float4v;

union U8 { uint4 u; short8 s; };

__device__ __forceinline__ ushort_t f2bf(float f) {
    unsigned u = __float_as_uint(f);
    unsigned r = (u + 0x7fffu + ((u >> 16) & 1u)) >> 16;
    return (ushort_t)r;
}
// fast round-to-nearest (ties up): 2 VALU  [validated round 9: absmax unchanged]
__device__ __forceinline__ ushort_t f2bfF(float f) {
    return (ushort_t)((__float_as_uint(f) + 0x8000u) >> 16);
}

__device__ __forceinline__ uint_t pkrn(uint_t lo, uint_t hi) {
    return ((lo + 0x8000u) >> 16) | ((hi + 0x8000u) & 0xffff0000u);
}

__device__ __forceinline__ short8 packG(const float* p8) {
    float4 a = *(const float4*)p8;
    float4 b = *(const float4*)(p8 + 4);
    U8 c;
    c.u.x = pkrn(__float_as_uint(a.x), __float_as_uint(a.y));
    c.u.y = pkrn(__float_as_uint(a.z), __float_as_uint(a.w));
    c.u.z = pkrn(__float_as_uint(b.x), __float_as_uint(b.y));
    c.u.w = pkrn(__float_as_uint(b.z), __float_as_uint(b.w));
    return c.s;
}

#define WBAR() do { asm volatile("s_waitcnt lgkmcnt(0)" ::: "memory"); \
                    __builtin_amdgcn_wave_barrier(); } while (0)

// ---------------------------------------------------------------------------
// Kernel 1 (MFMA): C[64 x 192] = x_tile[64x64] @ [Wq;Wk;Wv]^T + bias
// (unchanged — ~4 us)
// ---------------------------------------------------------------------------
__global__ __launch_bounds__(256) void k_qkv(
    const float* __restrict__ x,
    const float* __restrict__ Wq, const float* __restrict__ bq,
    const float* __restrict__ Wk, const float* __restrict__ bk,
    const float* __restrict__ Wv, const float* __restrict__ bv,
    float* __restrict__ xq, uint_t* __restrict__ kvp)
{
    __shared__ __align__(16) ushort_t sA[64 * 72];
    __shared__ __align__(16) ushort_t sB[192 * 72];

    const int tid  = threadIdx.x;
    const int lane = tid & 63;
    const int w    = tid >> 6;
    const int n0   = blockIdx.x * 64;

    const float4* xg = (const float4*)(x + (size_t)n0 * 64);
#pragma unroll
    for (int i = 0; i < 4; ++i) {
        int f = i * 256 + tid;
        float4 v = xg[f];
        int r = f >> 4, c4 = f & 15;
        uint2 pk;
        pk.x = (uint_t)f2bf(v.x) | ((uint_t)f2bf(v.y) << 16);
        pk.y = (uint_t)f2bf(v.z) | ((uint_t)f2bf(v.w) << 16);
        *(uint2*)(sA + r * 72 + c4 * 4) = pk;
    }
#pragma unroll
    for (int i = 0; i < 12; ++i) {
        const float* src = (i < 4) ? Wq : (i < 8) ? Wk : Wv;
        int f = i * 256 + tid;
        int r = f >> 4, c4 = f & 15;
        float4 v = ((const float4*)src)[(i & 3) * 256 + tid];
        uint2 pk;
        pk.x = (uint_t)f2bf(v.x) | ((uint_t)f2bf(v.y) << 16);
        pk.y = (uint_t)f2bf(v.z) | ((uint_t)f2bf(v.w) << 16);
        *(uint2*)(sB + r * 72 + c4 * 4) = pk;
    }
    __syncthreads();

    const int quad = lane >> 4;
    const int cn   = lane & 15;
    const int mrow = (w << 4) + cn;

    short8 a0 = *(const short8*)(sA + mrow * 72 + quad * 8);
    short8 a1 = *(const short8*)(sA + mrow * 72 + 32 + quad * 8);

    float4v acc[12];
#pragma unroll
    for (int t = 0; t < 12; ++t) {
        const int brow = t * 16 + cn;
        short8 b0 = *(const short8*)(sB + brow * 72 + quad * 8);
        short8 b1 = *(const short8*)(sB + brow * 72 + 32 + quad * 8);
        float4v c = {0.f, 0.f, 0.f, 0.f};
        c = __builtin_amdgcn_mfma_f32_16x16x32_bf16(a0, b0, c, 0, 0, 0);
        c = __builtin_amdgcn_mfma_f32_16x16x32_bf16(a1, b1, c, 0, 0, 0);
        acc[t] = c;
    }

    const int orow = n0 + (w << 4) + quad * 4;
#pragma unroll
    for (int t = 0; t < 4; ++t) {
        int o = t * 16 + cn;
        float bqv = bq[o], bkv = bk[o], bvv = bv[o];
        float4v aq = acc[t], ak = acc[4 + t], av = acc[8 + t];
#pragma unroll
        for (int r = 0; r < 4; ++r) {
            size_t base = (size_t)(orow + r) * 64 + o;
            xq[base]  = aq[r] + bqv;
            kvp[base] = (uint_t)f2bf(ak[r] + bkv) | ((uint_t)f2bf(av[r] + bvv) << 16);
        }
    }
}

// ---------------------------------------------------------------------------
// Kernel 2: round-8 structure (single-parity buffers, 21 KB LDS, per-point
// phase chain — TLP covers the drains) + fast bf16 round + no-max-sub
// softmax. launch_bounds(256,6): 6 blocks/CU (24 waves) — occupancy lever.
// ---------------------------------------------------------------------------
__global__ __launch_bounds__(256, 6) void k_attn(
    const float* __restrict__ p, const int* __restrict__ idx,
    const float* __restrict__ xq, const uint_t* __restrict__ kvp,
    const float* __restrict__ Wp1, const float* __restrict__ bp1,
    const float* __restrict__ pg, const float* __restrict__ pb,
    const float* __restrict__ pm, const float* __restrict__ pv,
    const float* __restrict__ Wp2, const float* __restrict__ bp2,
    const float* __restrict__ wg1, const float* __restrict__ wb1,
    const float* __restrict__ wm1, const float* __restrict__ wv1,
    const float* __restrict__ Ww1, const float* __restrict__ bw1,
    const float* __restrict__ wg2, const float* __restrict__ wb2,
    const float* __restrict__ wm2, const float* __restrict__ wv2,
    const float* __restrict__ Ww2, const float* __restrict__ bw2,
    float* __restrict__ out)
{
    __shared__ __align__(16) ushort_t swr[4][16 * 72];  // bf16 wrel, stride 72
    __shared__ __align__(16) ushort_t shl[4][16 * 40];  // bf16 h, K-padded
    __shared__ __align__(16) float    swt[4][4 * 16 * 4]; // t float4 per (pt,j)
    __shared__ __align__(16) float    swg[4][8 * 20];   // wgtT [m8][j], stride 20

    const int tid   = threadIdx.x;
    const int wid   = __builtin_amdgcn_readfirstlane(tid >> 6);
    const int lane  = tid & 63;
    const int nbase = blockIdx.x * 16 + wid * 4;

    ushort_t* wrelh = swr[wid];
    ushort_t* hLh   = shl[wid];
    float*    stt   = swt[wid];
    float*    wgt   = swg[wid];

    const int cm  = lane & 15;
    const int q   = lane >> 4;
    const int m8  = lane & 7;
    const int cmc = cm & 7;
    const bool colv = cm < 8;

    const int* idxr = idx + (size_t)nbase * 16;

    uint_t ga[16], gb[16];
    auto issueF = [&](int pt, uint_t (&dst)[16]) {
#pragma unroll
        for (int j = 0; j < 16; ++j) {
            int id = __builtin_amdgcn_readfirstlane(idxr[pt * 16 + j]);
            dst[j] = kvp[(size_t)id * 64 + lane];
        }
    };

    issueF(0, ga);
    issueF(1, gb);

    // zero-fill h K-pad region (cols 8..31 stay 0)
    {
        uint_t* hz = (uint_t*)hLh;
        for (int i = lane; i < 16 * 20; i += 64) hz[i] = 0u;
    }

    // ---- strip loads ----
    int   idv[4];
    float xqc[4];
#pragma unroll
    for (int pt = 0; pt < 4; ++pt) {
        idv[pt] = idxr[pt * 16 + cm];
        xqc[pt] = xq[(size_t)(nbase + pt) * 64 + lane];
    }
    float gpx[4], gpy[4], gpz[4];
#pragma unroll
    for (int pt = 0; pt < 4; ++pt) {
        gpx[pt] = p[idv[pt] * 3 + 0];
        gpy[pt] = p[idv[pt] * 3 + 1];
        gpz[pt] = p[idv[pt] * 3 + 2];
    }

    // ---- tiny uniform params (linear_p folded BN) ----
    float w100 = Wp1[0], w101 = Wp1[1], w102 = Wp1[2];
    float w110 = Wp1[3], w111 = Wp1[4], w112 = Wp1[5];
    float w120 = Wp1[6], w121 = Wp1[7], w122 = Wp1[8];
    float sp0 = pg[0] * rsqrtf(pv[0] + EPSV);
    float sp1 = pg[1] * rsqrtf(pv[1] + EPSV);
    float sp2 = pg[2] * rsqrtf(pv[2] + EPSV);
    float off0 = (bp1[0] - pm[0]) * sp0 + pb[0];
    float off1 = (bp1[1] - pm[1]) * sp1 + pb[1];
    float off2 = (bp1[2] - pm[2]) * sp2 + pb[2];

    // ---- per-lane params ----
    float s1 = wg1[lane] * rsqrtf(wv1[lane] + EPSV);
    float o1 = wb1[lane] - wm1[lane] * s1;
    float wp2x = Wp2[lane * 3 + 0], wp2y = Wp2[lane * 3 + 1], wp2z = Wp2[lane * 3 + 2];
    float peb = bp2[lane];

    float s2c = wg2[cmc] * rsqrtf(wv2[cmc] + EPSV);
    float o2c = wb2[cmc] - wm2[cmc] * s2c;
    float bw1c = bw1[cmc];

    // ---- MFMA B-fragments (registers, whole kernel) ----
    short8 bf1a, bf1b, bf2;
    {
        const float* r1 = Ww1 + cmc * 64 + q * 8;
        short8 t1a = packG(r1);
        short8 t1b = packG(r1 + 32);
        short8 t2  = packG(Ww2 + cmc * 8);
        U8 z; z.u = make_uint4(0u, 0u, 0u, 0u);
        bf1a = colv ? t1a : z.s;
        bf1b = colv ? t1b : z.s;
        bf2  = (colv && q == 0) ? t2 : z.s;
    }

    // ---- t-triples per (pt, slot=cm) -> LDS float4 table ----
#pragma unroll
    for (int pt = 0; pt < 4; ++pt) {
        int n = nbase + pt;
        float pcx = p[n * 3 + 0], pcy = p[n * 3 + 1], pcz = p[n * 3 + 2];
        float prx = gpx[pt] - pcx, pry = gpy[pt] - pcy, prz = gpz[pt] - pcz;
        float t0 = fmaxf(fmaf(fmaf(prx, w100, fmaf(pry, w101, prz * w102)), sp0, off0), 0.f);
        float t1 = fmaxf(fmaf(fmaf(prx, w110, fmaf(pry, w111, prz * w112)), sp1, off1), 0.f);
        float t2 = fmaxf(fmaf(fmaf(prx, w120, fmaf(pry, w121, prz * w122)), sp2, off2), 0.f);
        if (lane < 16) {
            *(float4*)(stt + (pt * 16 + cm) * 4) = make_float4(t0, t1, t2, 0.f);
        }
    }
    WBAR();

    auto computeF = [&](int pt, uint_t (&g)[16]) {
        float xqv = xqc[pt];
        float vpe[16];
        // ---- Phase A: pe + relation + bn1+relu -> wrel (bf16) ----
#pragma unroll
        for (int j = 0; j < 16; ++j) {
            float4 t = *(const float4*)(stt + (pt * 16 + j) * 4);   // broadcast
            float pe = fmaf(t.x, wp2x, fmaf(t.y, wp2y, fmaf(t.z, wp2z, peb)));
            float xkj = __uint_as_float(g[j] << 16);
            float xvj = __uint_as_float(g[j] & 0xffff0000u);
            vpe[j] = xvj + pe;
            float d = (xkj - xqv) + pe;
            wrelh[j * 72 + lane] = f2bfF(fmaxf(fmaf(d, s1, o1), 0.f));
        }
        WBAR();

        // ---- Phase B1 (MFMA): wrel[16x64] @ Ww1^T -> bn2+relu -> hL (bf16) ----
        short8 a1a = *(const short8*)(wrelh + cm * 72 + q * 8);
        short8 a1b = *(const short8*)(wrelh + cm * 72 + 32 + q * 8);
        float4v d1 = {0.f, 0.f, 0.f, 0.f};
        d1 = __builtin_amdgcn_mfma_f32_16x16x32_bf16(a1a, bf1a, d1, 0, 0, 0);
        d1 = __builtin_amdgcn_mfma_f32_16x16x32_bf16(a1b, bf1b, d1, 0, 0, 0);
#pragma unroll
        for (int r = 0; r < 4; ++r) {
            float hv = fmaxf(fmaf(d1[r] + bw1c, s2c, o2c), 0.f);
            if (colv) hLh[(q * 4 + r) * 40 + cm] = f2bfF(hv);
        }
        WBAR();

        // ---- Phase B2 (MFMA, K=8 zero-padded): h @ Ww2^T -> logits ----
        short8 a2 = *(const short8*)(hLh + cm * 40 + q * 8);
        float4v d2 = {0.f, 0.f, 0.f, 0.f};
        d2 = __builtin_amdgcn_mfma_f32_16x16x32_bf16(a2, bf2, d2, 0, 0, 0);

        // ---- Phase C: softmax over j, no max-sub (logits bounded) ----
        float e0 = __expf(d2[0]), e1 = __expf(d2[1]);
        float e2 = __expf(d2[2]), e3 = __expf(d2[3]);
        float ss = (e0 + e1) + (e2 + e3);
        ss += __shfl_xor(ss, 16);
        ss += __shfl_xor(ss, 32);
        float inv = 1.f / ss;
        if (colv) {
            *(float4*)(wgt + cm * 20 + q * 4) =
                make_float4(e0 * inv, e1 * inv, e2 * inv, e3 * inv);
        }
        WBAR();

        // ---- weighted sum over neighbors (4 b128 broadcast reads) ----
        float acc = 0.f;
#pragma unroll
        for (int gq = 0; gq < 4; ++gq) {
            float4 wv4 = *(const float4*)(wgt + m8 * 20 + gq * 4);
            acc = fmaf(wv4.x, vpe[gq * 4 + 0], acc);
            acc = fmaf(wv4.y, vpe[gq * 4 + 1], acc);
            acc = fmaf(wv4.z, vpe[gq * 4 + 2], acc);
            acc = fmaf(wv4.w, vpe[gq * 4 + 3], acc);
        }
        WBAR();
        out[(size_t)(nbase + pt) * 64 + lane] = acc;
    };

    // 2-deep pipelined strip
    computeF(0, ga);
    issueF(2, ga);
    computeF(1, gb);
    issueF(3, gb);
    computeF(2, ga);
    computeF(3, gb);
}

extern "C" void kernel_launch(void* const* d_in, const int* in_sizes, int n_in,
                              void* d_out, int out_size, void* d_ws, size_t ws_size,
                              hipStream_t stream) {
    const float* p   = (const float*)d_in[0];
    const float* x   = (const float*)d_in[1];
    const int*   idx = (const int*)d_in[2];
    const float* Wq  = (const float*)d_in[3];  const float* bq  = (const float*)d_in[4];
    const float* Wk  = (const float*)d_in[5];  const float* bk  = (const float*)d_in[6];
    const float* Wv  = (const float*)d_in[7];  const float* bv  = (const float*)d_in[8];
    const float* Wp1 = (const float*)d_in[9];  const float* bp1 = (const float*)d_in[10];
    const float* pg  = (const float*)d_in[11]; const float* pb  = (const float*)d_in[12];
    const float* pm  = (const float*)d_in[13]; const float* pv  = (const float*)d_in[14];
    const float* Wp2 = (const float*)d_in[15]; const float* bp2 = (const float*)d_in[16];
    const float* wg1 = (const float*)d_in[17]; const float* wb1 = (const float*)d_in[18];
    const float* wm1 = (const float*)d_in[19]; const float* wv1 = (const float*)d_in[20];
    const float* Ww1 = (const float*)d_in[21]; const float* bw1 = (const float*)d_in[22];
    const float* wg2 = (const float*)d_in[23]; const float* wb2 = (const float*)d_in[24];
    const float* wm2 = (const float*)d_in[25]; const float* wv2 = (const float*)d_in[26];
    const float* Ww2 = (const float*)d_in[27]; const float* bw2 = (const float*)d_in[28];

    float*  xqw = (float*)d_ws;
    uint_t* kvw = (uint_t*)((char*)d_ws + (size_t)NPTS * 64 * sizeof(float));
    float*  outp = (float*)d_out;

    k_qkv<<<dim3(NPTS / 64), dim3(256), 0, stream>>>(x, Wq, bq, Wk, bk, Wv, bv, xqw, kvw);
    k_attn<<<dim3(NPTS / 16), dim3(256), 0, stream>>>(p, idx, xqw, kvw,
                                                      Wp1, bp1, pg, pb, pm, pv, Wp2, bp2,
                                                      wg1, wb1, wm1, wv1, Ww1, bw1,
                                                      wg2, wb2, wm2, wv2, Ww2, bw2, outp);
}

// Round 11
// 204.692 us; speedup vs baseline: 1.2009x; 1.2009x over previous
//
#include <hip/hip_runtime.h>

#define NPTS 65536
#define EPSV 1e-5f

typedef unsigned int uint_t;
typedef unsigned short ushort_t;
typedef __attribute__((ext_vector_type(8))) short short8;
typedef __attribute__((ext_vector_type(4))) float float4v;

union U8 { uint4 u; short8 s; };

__device__ __forceinline__ ushort_t f2bf(float f) {
    unsigned u = __float_as_uint(f);
    unsigned r = (u + 0x7fffu + ((u >> 16) & 1u)) >> 16;
    return (ushort_t)r;
}
// fast round-to-nearest (ties up): 2 VALU  [validated rounds 9/10: absmax unchanged]
__device__ __forceinline__ ushort_t f2bfF(float f) {
    return (ushort_t)((__float_as_uint(f) + 0x8000u) >> 16);
}

__device__ __forceinline__ uint_t pkrn(uint_t lo, uint_t hi) {
    return ((lo + 0x8000u) >> 16) | ((hi + 0x8000u) & 0xffff0000u);
}

__device__ __forceinline__ short8 packG(const float* p8) {
    float4 a = *(const float4*)p8;
    float4 b = *(const float4*)(p8 + 4);
    U8 c;
    c.u.x = pkrn(__float_as_uint(a.x), __float_as_uint(a.y));
    c.u.y = pkrn(__float_as_uint(a.z), __float_as_uint(a.w));
    c.u.z = pkrn(__float_as_uint(b.x), __float_as_uint(b.y));
    c.u.w = pkrn(__float_as_uint(b.z), __float_as_uint(b.w));
    return c.s;
}

#define WBAR() do { asm volatile("s_waitcnt lgkmcnt(0)" ::: "memory"); \
                    __builtin_amdgcn_wave_barrier(); } while (0)

// ---------------------------------------------------------------------------
// Kernel 1 (MFMA): C[64 x 192] = x_tile[64x64] @ [Wq;Wk;Wv]^T + bias
// (unchanged — ~4 us)
// ---------------------------------------------------------------------------
__global__ __launch_bounds__(256) void k_qkv(
    const float* __restrict__ x,
    const float* __restrict__ Wq, const float* __restrict__ bq,
    const float* __restrict__ Wk, const float* __restrict__ bk,
    const float* __restrict__ Wv, const float* __restrict__ bv,
    float* __restrict__ xq, uint_t* __restrict__ kvp)
{
    __shared__ __align__(16) ushort_t sA[64 * 72];
    __shared__ __align__(16) ushort_t sB[192 * 72];

    const int tid  = threadIdx.x;
    const int lane = tid & 63;
    const int w    = tid >> 6;
    const int n0   = blockIdx.x * 64;

    const float4* xg = (const float4*)(x + (size_t)n0 * 64);
#pragma unroll
    for (int i = 0; i < 4; ++i) {
        int f = i * 256 + tid;
        float4 v = xg[f];
        int r = f >> 4, c4 = f & 15;
        uint2 pk;
        pk.x = (uint_t)f2bf(v.x) | ((uint_t)f2bf(v.y) << 16);
        pk.y = (uint_t)f2bf(v.z) | ((uint_t)f2bf(v.w) << 16);
        *(uint2*)(sA + r * 72 + c4 * 4) = pk;
    }
#pragma unroll
    for (int i = 0; i < 12; ++i) {
        const float* src = (i < 4) ? Wq : (i < 8) ? Wk : Wv;
        int f = i * 256 + tid;
        int r = f >> 4, c4 = f & 15;
        float4 v = ((const float4*)src)[(i & 3) * 256 + tid];
        uint2 pk;
        pk.x = (uint_t)f2bf(v.x) | ((uint_t)f2bf(v.y) << 16);
        pk.y = (uint_t)f2bf(v.z) | ((uint_t)f2bf(v.w) << 16);
        *(uint2*)(sB + r * 72 + c4 * 4) = pk;
    }
    __syncthreads();

    const int quad = lane >> 4;
    const int cn   = lane & 15;
    const int mrow = (w << 4) + cn;

    short8 a0 = *(const short8*)(sA + mrow * 72 + quad * 8);
    short8 a1 = *(const short8*)(sA + mrow * 72 + 32 + quad * 8);

    float4v acc[12];
#pragma unroll
    for (int t = 0; t < 12; ++t) {
        const int brow = t * 16 + cn;
        short8 b0 = *(const short8*)(sB + brow * 72 + quad * 8);
        short8 b1 = *(const short8*)(sB + brow * 72 + 32 + quad * 8);
        float4v c = {0.f, 0.f, 0.f, 0.f};
        c = __builtin_amdgcn_mfma_f32_16x16x32_bf16(a0, b0, c, 0, 0, 0);
        c = __builtin_amdgcn_mfma_f32_16x16x32_bf16(a1, b1, c, 0, 0, 0);
        acc[t] = c;
    }

    const int orow = n0 + (w << 4) + quad * 4;
#pragma unroll
    for (int t = 0; t < 4; ++t) {
        int o = t * 16 + cn;
        float bqv = bq[o], bkv = bk[o], bvv = bv[o];
        float4v aq = acc[t], ak = acc[4 + t], av = acc[8 + t];
#pragma unroll
        for (int r = 0; r < 4; ++r) {
            size_t base = (size_t)(orow + r) * 64 + o;
            xq[base]  = aq[r] + bqv;
            kvp[base] = (uint_t)f2bf(ak[r] + bkv) | ((uint_t)f2bf(av[r] + bvv) << 16);
        }
    }
}

// ---------------------------------------------------------------------------
// Kernel 2: round-8 structure (single-parity buffers, 21 KB LDS, per-point
// phase chain — TLP covers the drains) + fast bf16 round + no-max-sub
// softmax. launch_bounds(256,5): 102-VGPR cap (>= ~76 natural demand, so no
// spill) while allowing 5 blocks/CU. [(256,6)->40VGPR+spill was the r10 bug]
// ---------------------------------------------------------------------------
__global__ __launch_bounds__(256, 5) void k_attn(
    const float* __restrict__ p, const int* __restrict__ idx,
    const float* __restrict__ xq, const uint_t* __restrict__ kvp,
    const float* __restrict__ Wp1, const float* __restrict__ bp1,
    const float* __restrict__ pg, const float* __restrict__ pb,
    const float* __restrict__ pm, const float* __restrict__ pv,
    const float* __restrict__ Wp2, const float* __restrict__ bp2,
    const float* __restrict__ wg1, const float* __restrict__ wb1,
    const float* __restrict__ wm1, const float* __restrict__ wv1,
    const float* __restrict__ Ww1, const float* __restrict__ bw1,
    const float* __restrict__ wg2, const float* __restrict__ wb2,
    const float* __restrict__ wm2, const float* __restrict__ wv2,
    const float* __restrict__ Ww2, const float* __restrict__ bw2,
    float* __restrict__ out)
{
    __shared__ __align__(16) ushort_t swr[4][16 * 72];  // bf16 wrel, stride 72
    __shared__ __align__(16) ushort_t shl[4][16 * 40];  // bf16 h, K-padded
    __shared__ __align__(16) float    swt[4][4 * 16 * 4]; // t float4 per (pt,j)
    __shared__ __align__(16) float    swg[4][8 * 20];   // wgtT [m8][j], stride 20

    const int tid   = threadIdx.x;
    const int wid   = __builtin_amdgcn_readfirstlane(tid >> 6);
    const int lane  = tid & 63;
    const int nbase = blockIdx.x * 16 + wid * 4;

    ushort_t* wrelh = swr[wid];
    ushort_t* hLh   = shl[wid];
    float*    stt   = swt[wid];
    float*    wgt   = swg[wid];

    const int cm  = lane & 15;
    const int q   = lane >> 4;
    const int m8  = lane & 7;
    const int cmc = cm & 7;
    const bool colv = cm < 8;

    const int* idxr = idx + (size_t)nbase * 16;

    uint_t ga[16], gb[16];
    auto issueF = [&](int pt, uint_t (&dst)[16]) {
#pragma unroll
        for (int j = 0; j < 16; ++j) {
            int id = __builtin_amdgcn_readfirstlane(idxr[pt * 16 + j]);
            dst[j] = kvp[(size_t)id * 64 + lane];
        }
    };

    issueF(0, ga);
    issueF(1, gb);

    // zero-fill h K-pad region (cols 8..31 stay 0)
    {
        uint_t* hz = (uint_t*)hLh;
        for (int i = lane; i < 16 * 20; i += 64) hz[i] = 0u;
    }

    // ---- strip loads ----
    int   idv[4];
    float xqc[4];
#pragma unroll
    for (int pt = 0; pt < 4; ++pt) {
        idv[pt] = idxr[pt * 16 + cm];
        xqc[pt] = xq[(size_t)(nbase + pt) * 64 + lane];
    }
    float gpx[4], gpy[4], gpz[4];
#pragma unroll
    for (int pt = 0; pt < 4; ++pt) {
        gpx[pt] = p[idv[pt] * 3 + 0];
        gpy[pt] = p[idv[pt] * 3 + 1];
        gpz[pt] = p[idv[pt] * 3 + 2];
    }

    // ---- tiny uniform params (linear_p folded BN) ----
    float w100 = Wp1[0], w101 = Wp1[1], w102 = Wp1[2];
    float w110 = Wp1[3], w111 = Wp1[4], w112 = Wp1[5];
    float w120 = Wp1[6], w121 = Wp1[7], w122 = Wp1[8];
    float sp0 = pg[0] * rsqrtf(pv[0] + EPSV);
    float sp1 = pg[1] * rsqrtf(pv[1] + EPSV);
    float sp2 = pg[2] * rsqrtf(pv[2] + EPSV);
    float off0 = (bp1[0] - pm[0]) * sp0 + pb[0];
    float off1 = (bp1[1] - pm[1]) * sp1 + pb[1];
    float off2 = (bp1[2] - pm[2]) * sp2 + pb[2];

    // ---- per-lane params ----
    float s1 = wg1[lane] * rsqrtf(wv1[lane] + EPSV);
    float o1 = wb1[lane] - wm1[lane] * s1;
    float wp2x = Wp2[lane * 3 + 0], wp2y = Wp2[lane * 3 + 1], wp2z = Wp2[lane * 3 + 2];
    float peb = bp2[lane];

    float s2c = wg2[cmc] * rsqrtf(wv2[cmc] + EPSV);
    float o2c = wb2[cmc] - wm2[cmc] * s2c;
    float bw1c = bw1[cmc];

    // ---- MFMA B-fragments (registers, whole kernel) ----
    short8 bf1a, bf1b, bf2;
    {
        const float* r1 = Ww1 + cmc * 64 + q * 8;
        short8 t1a = packG(r1);
        short8 t1b = packG(r1 + 32);
        short8 t2  = packG(Ww2 + cmc * 8);
        U8 z; z.u = make_uint4(0u, 0u, 0u, 0u);
        bf1a = colv ? t1a : z.s;
        bf1b = colv ? t1b : z.s;
        bf2  = (colv && q == 0) ? t2 : z.s;
    }

    // ---- t-triples per (pt, slot=cm) -> LDS float4 table ----
#pragma unroll
    for (int pt = 0; pt < 4; ++pt) {
        int n = nbase + pt;
        float pcx = p[n * 3 + 0], pcy = p[n * 3 + 1], pcz = p[n * 3 + 2];
        float prx = gpx[pt] - pcx, pry = gpy[pt] - pcy, prz = gpz[pt] - pcz;
        float t0 = fmaxf(fmaf(fmaf(prx, w100, fmaf(pry, w101, prz * w102)), sp0, off0), 0.f);
        float t1 = fmaxf(fmaf(fmaf(prx, w110, fmaf(pry, w111, prz * w112)), sp1, off1), 0.f);
        float t2 = fmaxf(fmaf(fmaf(prx, w120, fmaf(pry, w121, prz * w122)), sp2, off2), 0.f);
        if (lane < 16) {
            *(float4*)(stt + (pt * 16 + cm) * 4) = make_float4(t0, t1, t2, 0.f);
        }
    }
    WBAR();

    auto computeF = [&](int pt, uint_t (&g)[16]) {
        float xqv = xqc[pt];
        float vpe[16];
        // ---- Phase A: pe + relation + bn1+relu -> wrel (bf16) ----
#pragma unroll
        for (int j = 0; j < 16; ++j) {
            float4 t = *(const float4*)(stt + (pt * 16 + j) * 4);   // broadcast
            float pe = fmaf(t.x, wp2x, fmaf(t.y, wp2y, fmaf(t.z, wp2z, peb)));
            float xkj = __uint_as_float(g[j] << 16);
            float xvj = __uint_as_float(g[j] & 0xffff0000u);
            vpe[j] = xvj + pe;
            float d = (xkj - xqv) + pe;
            wrelh[j * 72 + lane] = f2bfF(fmaxf(fmaf(d, s1, o1), 0.f));
        }
        WBAR();

        // ---- Phase B1 (MFMA): wrel[16x64] @ Ww1^T -> bn2+relu -> hL (bf16) ----
        short8 a1a = *(const short8*)(wrelh + cm * 72 + q * 8);
        short8 a1b = *(const short8*)(wrelh + cm * 72 + 32 + q * 8);
        float4v d1 = {0.f, 0.f, 0.f, 0.f};
        d1 = __builtin_amdgcn_mfma_f32_16x16x32_bf16(a1a, bf1a, d1, 0, 0, 0);
        d1 = __builtin_amdgcn_mfma_f32_16x16x32_bf16(a1b, bf1b, d1, 0, 0, 0);
#pragma unroll
        for (int r = 0; r < 4; ++r) {
            float hv = fmaxf(fmaf(d1[r] + bw1c, s2c, o2c), 0.f);
            if (colv) hLh[(q * 4 + r) * 40 + cm] = f2bfF(hv);
        }
        WBAR();

        // ---- Phase B2 (MFMA, K=8 zero-padded): h @ Ww2^T -> logits ----
        short8 a2 = *(const short8*)(hLh + cm * 40 + q * 8);
        float4v d2 = {0.f, 0.f, 0.f, 0.f};
        d2 = __builtin_amdgcn_mfma_f32_16x16x32_bf16(a2, bf2, d2, 0, 0, 0);

        // ---- Phase C: softmax over j, no max-sub (logits bounded) ----
        float e0 = __expf(d2[0]), e1 = __expf(d2[1]);
        float e2 = __expf(d2[2]), e3 = __expf(d2[3]);
        float ss = (e0 + e1) + (e2 + e3);
        ss += __shfl_xor(ss, 16);
        ss += __shfl_xor(ss, 32);
        float inv = 1.f / ss;
        if (colv) {
            *(float4*)(wgt + cm * 20 + q * 4) =
                make_float4(e0 * inv, e1 * inv, e2 * inv, e3 * inv);
        }
        WBAR();

        // ---- weighted sum over neighbors (4 b128 broadcast reads) ----
        float acc = 0.f;
#pragma unroll
        for (int gq = 0; gq < 4; ++gq) {
            float4 wv4 = *(const float4*)(wgt + m8 * 20 + gq * 4);
            acc = fmaf(wv4.x, vpe[gq * 4 + 0], acc);
            acc = fmaf(wv4.y, vpe[gq * 4 + 1], acc);
            acc = fmaf(wv4.z, vpe[gq * 4 + 2], acc);
            acc = fmaf(wv4.w, vpe[gq * 4 + 3], acc);
        }
        WBAR();
        out[(size_t)(nbase + pt) * 64 + lane] = acc;
    };

    // 2-deep pipelined strip
    computeF(0, ga);
    issueF(2, ga);
    computeF(1, gb);
    issueF(3, gb);
    computeF(2, ga);
    computeF(3, gb);
}

extern "C" void kernel_launch(void* const* d_in, const int* in_sizes, int n_in,
                              void* d_out, int out_size, void* d_ws, size_t ws_size,
                              hipStream_t stream) {
    const float* p   = (const float*)d_in[0];
    const float* x   = (const float*)d_in[1];
    const int*   idx = (const int*)d_in[2];
    const float* Wq  = (const float*)d_in[3];  const float* bq  = (const float*)d_in[4];
    const float* Wk  = (const float*)d_in[5];  const float* bk  = (const float*)d_in[6];
    const float* Wv  = (const float*)d_in[7];  const float* bv  = (const float*)d_in[8];
    const float* Wp1 = (const float*)d_in[9];  const float* bp1 = (const float*)d_in[10];
    const float* pg  = (const float*)d_in[11]; const float* pb  = (const float*)d_in[12];
    const float* pm  = (const float*)d_in[13]; const float* pv  = (const float*)d_in[14];
    const float* Wp2 = (const float*)d_in[15]; const float* bp2 = (const float*)d_in[16];
    const float* wg1 = (const float*)d_in[17]; const float* wb1 = (const float*)d_in[18];
    const float* wm1 = (const float*)d_in[19]; const float* wv1 = (const float*)d_in[20];
    const float* Ww1 = (const float*)d_in[21]; const float* bw1 = (const float*)d_in[22];
    const float* wg2 = (const float*)d_in[23]; const float* wb2 = (const float*)d_in[24];
    const float* wm2 = (const float*)d_in[25]; const float* wv2 = (const float*)d_in[26];
    const float* Ww2 = (const float*)d_in[27]; const float* bw2 = (const float*)d_in[28];

    float*  xqw = (float*)d_ws;
    uint_t* kvw = (uint_t*)((char*)d_ws + (size_t)NPTS * 64 * sizeof(float));
    float*  outp = (float*)d_out;

    k_qkv<<<dim3(NPTS / 64), dim3(256), 0, stream>>>(x, Wq, bq, Wk, bk, Wv, bv, xqw, kvw);
    k_attn<<<dim3(NPTS / 16), dim3(256), 0, stream>>>(p, idx, xqw, kvw,
                                                      Wp1, bp1, pg, pb, pm, pv, Wp2, bp2,
                                                      wg1, wb1, wm1, wv1, Ww1, bw1,
                                                      wg2, wb2, wm2, wv2, Ww2, bw2, outp);
}

// Round 12
// 181.739 us; speedup vs baseline: 1.3525x; 1.1263x over previous
//
#include <hip/hip_runtime.h>

#define NPTS 65536
#define EPSV 1e-5f

typedef unsigned int uint_t;
typedef unsigned short ushort_t;
typedef __attribute__((ext_vector_type(8))) short short8;
typedef __attribute__((ext_vector_type(4))) float float4v;

union U8 { uint4 u; short8 s; };

__device__ __forceinline__ ushort_t f2bf(float f) {
    unsigned u = __float_as_uint(f);
    unsigned r = (u + 0x7fffu + ((u >> 16) & 1u)) >> 16;
    return (ushort_t)r;
}
// fast round-to-nearest (ties up): 2 VALU  [validated r9-r11: absmax unchanged]
__device__ __forceinline__ ushort_t f2bfF(float f) {
    return (ushort_t)((__float_as_uint(f) + 0x8000u) >> 16);
}

__device__ __forceinline__ uint_t pkrn(uint_t lo, uint_t hi) {
    return ((lo + 0x8000u) >> 16) | ((hi + 0x8000u) & 0xffff0000u);
}

__device__ __forceinline__ short8 packG(const float* p8) {
    float4 a = *(const float4*)p8;
    float4 b = *(const float4*)(p8 + 4);
    U8 c;
    c.u.x = pkrn(__float_as_uint(a.x), __float_as_uint(a.y));
    c.u.y = pkrn(__float_as_uint(a.z), __float_as_uint(a.w));
    c.u.z = pkrn(__float_as_uint(b.x), __float_as_uint(b.y));
    c.u.w = pkrn(__float_as_uint(b.z), __float_as_uint(b.w));
    return c.s;
}

// Compile-only ordering fence: preserves LDS program order (vs TBAA
// reordering) with NO hardware drain. Per-wave LDS is in-order in HW;
// the compiler inserts minimal lgkmcnt before data use.
#define CBAR() asm volatile("" ::: "memory")

// ---------------------------------------------------------------------------
// Kernel 1 (MFMA): C[64 x 192] = x_tile[64x64] @ [Wq;Wk;Wv]^T + bias
// (unchanged — ~4 us)
// ---------------------------------------------------------------------------
__global__ __launch_bounds__(256) void k_qkv(
    const float* __restrict__ x,
    const float* __restrict__ Wq, const float* __restrict__ bq,
    const float* __restrict__ Wk, const float* __restrict__ bk,
    const float* __restrict__ Wv, const float* __restrict__ bv,
    float* __restrict__ xq, uint_t* __restrict__ kvp)
{
    __shared__ __align__(16) ushort_t sA[64 * 72];
    __shared__ __align__(16) ushort_t sB[192 * 72];

    const int tid  = threadIdx.x;
    const int lane = tid & 63;
    const int w    = tid >> 6;
    const int n0   = blockIdx.x * 64;

    const float4* xg = (const float4*)(x + (size_t)n0 * 64);
#pragma unroll
    for (int i = 0; i < 4; ++i) {
        int f = i * 256 + tid;
        float4 v = xg[f];
        int r = f >> 4, c4 = f & 15;
        uint2 pk;
        pk.x = (uint_t)f2bf(v.x) | ((uint_t)f2bf(v.y) << 16);
        pk.y = (uint_t)f2bf(v.z) | ((uint_t)f2bf(v.w) << 16);
        *(uint2*)(sA + r * 72 + c4 * 4) = pk;
    }
#pragma unroll
    for (int i = 0; i < 12; ++i) {
        const float* src = (i < 4) ? Wq : (i < 8) ? Wk : Wv;
        int f = i * 256 + tid;
        int r = f >> 4, c4 = f & 15;
        float4 v = ((const float4*)src)[(i & 3) * 256 + tid];
        uint2 pk;
        pk.x = (uint_t)f2bf(v.x) | ((uint_t)f2bf(v.y) << 16);
        pk.y = (uint_t)f2bf(v.z) | ((uint_t)f2bf(v.w) << 16);
        *(uint2*)(sB + r * 72 + c4 * 4) = pk;
    }
    __syncthreads();

    const int quad = lane >> 4;
    const int cn   = lane & 15;
    const int mrow = (w << 4) + cn;

    short8 a0 = *(const short8*)(sA + mrow * 72 + quad * 8);
    short8 a1 = *(const short8*)(sA + mrow * 72 + 32 + quad * 8);

    float4v acc[12];
#pragma unroll
    for (int t = 0; t < 12; ++t) {
        const int brow = t * 16 + cn;
        short8 b0 = *(const short8*)(sB + brow * 72 + quad * 8);
        short8 b1 = *(const short8*)(sB + brow * 72 + 32 + quad * 8);
        float4v c = {0.f, 0.f, 0.f, 0.f};
        c = __builtin_amdgcn_mfma_f32_16x16x32_bf16(a0, b0, c, 0, 0, 0);
        c = __builtin_amdgcn_mfma_f32_16x16x32_bf16(a1, b1, c, 0, 0, 0);
        acc[t] = c;
    }

    const int orow = n0 + (w << 4) + quad * 4;
#pragma unroll
    for (int t = 0; t < 4; ++t) {
        int o = t * 16 + cn;
        float bqv = bq[o], bkv = bk[o], bvv = bv[o];
        float4v aq = acc[t], ak = acc[4 + t], av = acc[8 + t];
#pragma unroll
        for (int r = 0; r < 4; ++r) {
            size_t base = (size_t)(orow + r) * 64 + o;
            xq[base]  = aq[r] + bqv;
            kvp[base] = (uint_t)f2bf(ak[r] + bkv) | ((uint_t)f2bf(av[r] + bvv) << 16);
        }
    }
}

// ---------------------------------------------------------------------------
// Kernel 2: round-8 structure at launch_bounds(256,4) [proven: 56 VGPR, no
// spill, 57 us]. Change vs r8: WBAR (full lgkmcnt(0) drain) -> CBAR
// (compile-only fence; HW per-wave in-order LDS gives ordering for free),
// and bn1 xq-offset folded per point.
// ---------------------------------------------------------------------------
__global__ __launch_bounds__(256, 4) void k_attn(
    const float* __restrict__ p, const int* __restrict__ idx,
    const float* __restrict__ xq, const uint_t* __restrict__ kvp,
    const float* __restrict__ Wp1, const float* __restrict__ bp1,
    const float* __restrict__ pg, const float* __restrict__ pb,
    const float* __restrict__ pm, const float* __restrict__ pv,
    const float* __restrict__ Wp2, const float* __restrict__ bp2,
    const float* __restrict__ wg1, const float* __restrict__ wb1,
    const float* __restrict__ wm1, const float* __restrict__ wv1,
    const float* __restrict__ Ww1, const float* __restrict__ bw1,
    const float* __restrict__ wg2, const float* __restrict__ wb2,
    const float* __restrict__ wm2, const float* __restrict__ wv2,
    const float* __restrict__ Ww2, const float* __restrict__ bw2,
    float* __restrict__ out)
{
    __shared__ __align__(16) ushort_t swr[4][16 * 72];  // bf16 wrel, stride 72
    __shared__ __align__(16) ushort_t shl[4][16 * 40];  // bf16 h, K-padded
    __shared__ __align__(16) float    swt[4][4 * 16 * 4]; // t float4 per (pt,j)
    __shared__ __align__(16) float    swg[4][8 * 20];   // wgtT [m8][j], stride 20

    const int tid   = threadIdx.x;
    const int wid   = __builtin_amdgcn_readfirstlane(tid >> 6);
    const int lane  = tid & 63;
    const int nbase = blockIdx.x * 16 + wid * 4;

    ushort_t* wrelh = swr[wid];
    ushort_t* hLh   = shl[wid];
    float*    stt   = swt[wid];
    float*    wgt   = swg[wid];

    const int cm  = lane & 15;
    const int q   = lane >> 4;
    const int m8  = lane & 7;
    const int cmc = cm & 7;
    const bool colv = cm < 8;

    const int* idxr = idx + (size_t)nbase * 16;

    uint_t ga[16], gb[16];
    auto issueF = [&](int pt, uint_t (&dst)[16]) {
#pragma unroll
        for (int j = 0; j < 16; ++j) {
            int id = __builtin_amdgcn_readfirstlane(idxr[pt * 16 + j]);
            dst[j] = kvp[(size_t)id * 64 + lane];
        }
    };

    issueF(0, ga);
    issueF(1, gb);

    // zero-fill h K-pad region (cols 8..31 stay 0)
    {
        uint_t* hz = (uint_t*)hLh;
        for (int i = lane; i < 16 * 20; i += 64) hz[i] = 0u;
    }
    CBAR();

    // ---- strip loads ----
    int   idv[4];
    float xqc[4];
#pragma unroll
    for (int pt = 0; pt < 4; ++pt) {
        idv[pt] = idxr[pt * 16 + cm];
        xqc[pt] = xq[(size_t)(nbase + pt) * 64 + lane];
    }
    float gpx[4], gpy[4], gpz[4];
#pragma unroll
    for (int pt = 0; pt < 4; ++pt) {
        gpx[pt] = p[idv[pt] * 3 + 0];
        gpy[pt] = p[idv[pt] * 3 + 1];
        gpz[pt] = p[idv[pt] * 3 + 2];
    }

    // ---- tiny uniform params (linear_p folded BN) ----
    float w100 = Wp1[0], w101 = Wp1[1], w102 = Wp1[2];
    float w110 = Wp1[3], w111 = Wp1[4], w112 = Wp1[5];
    float w120 = Wp1[6], w121 = Wp1[7], w122 = Wp1[8];
    float sp0 = pg[0] * rsqrtf(pv[0] + EPSV);
    float sp1 = pg[1] * rsqrtf(pv[1] + EPSV);
    float sp2 = pg[2] * rsqrtf(pv[2] + EPSV);
    float off0 = (bp1[0] - pm[0]) * sp0 + pb[0];
    float off1 = (bp1[1] - pm[1]) * sp1 + pb[1];
    float off2 = (bp1[2] - pm[2]) * sp2 + pb[2];

    // ---- per-lane params ----
    float s1 = wg1[lane] * rsqrtf(wv1[lane] + EPSV);
    float o1 = wb1[lane] - wm1[lane] * s1;
    float wp2x = Wp2[lane * 3 + 0], wp2y = Wp2[lane * 3 + 1], wp2z = Wp2[lane * 3 + 2];
    float peb = bp2[lane];

    float s2c = wg2[cmc] * rsqrtf(wv2[cmc] + EPSV);
    float o2c = wb2[cmc] - wm2[cmc] * s2c;
    float bw1c = bw1[cmc];

    // ---- MFMA B-fragments (registers, whole kernel) ----
    short8 bf1a, bf1b, bf2;
    {
        const float* r1 = Ww1 + cmc * 64 + q * 8;
        short8 t1a = packG(r1);
        short8 t1b = packG(r1 + 32);
        short8 t2  = packG(Ww2 + cmc * 8);
        U8 z; z.u = make_uint4(0u, 0u, 0u, 0u);
        bf1a = colv ? t1a : z.s;
        bf1b = colv ? t1b : z.s;
        bf2  = (colv && q == 0) ? t2 : z.s;
    }

    // ---- bn1 offset with xq folded in: qoff = o1 - xq*s1 ----
    float qoff[4];
#pragma unroll
    for (int pt = 0; pt < 4; ++pt) qoff[pt] = fmaf(-xqc[pt], s1, o1);

    // ---- t-triples per (pt, slot=cm) -> LDS float4 table ----
#pragma unroll
    for (int pt = 0; pt < 4; ++pt) {
        int n = nbase + pt;
        float pcx = p[n * 3 + 0], pcy = p[n * 3 + 1], pcz = p[n * 3 + 2];
        float prx = gpx[pt] - pcx, pry = gpy[pt] - pcy, prz = gpz[pt] - pcz;
        float t0 = fmaxf(fmaf(fmaf(prx, w100, fmaf(pry, w101, prz * w102)), sp0, off0), 0.f);
        float t1 = fmaxf(fmaf(fmaf(prx, w110, fmaf(pry, w111, prz * w112)), sp1, off1), 0.f);
        float t2 = fmaxf(fmaf(fmaf(prx, w120, fmaf(pry, w121, prz * w122)), sp2, off2), 0.f);
        if (lane < 16) {
            *(float4*)(stt + (pt * 16 + cm) * 4) = make_float4(t0, t1, t2, 0.f);
        }
    }
    CBAR();

    auto computeF = [&](int pt, uint_t (&g)[16]) {
        float qo = qoff[pt];
        float vpe[16];
        // ---- Phase A: pe + relation + bn1+relu -> wrel (bf16) ----
#pragma unroll
        for (int j = 0; j < 16; ++j) {
            float4 t = *(const float4*)(stt + (pt * 16 + j) * 4);   // broadcast
            float pe = fmaf(t.x, wp2x, fmaf(t.y, wp2y, fmaf(t.z, wp2z, peb)));
            float xkj = __uint_as_float(g[j] << 16);
            float xvj = __uint_as_float(g[j] & 0xffff0000u);
            vpe[j] = xvj + pe;
            wrelh[j * 72 + lane] = f2bfF(fmaxf(fmaf(xkj + pe, s1, qo), 0.f));
        }
        CBAR();

        // ---- Phase B1 (MFMA): wrel[16x64] @ Ww1^T -> bn2+relu -> hL (bf16) ----
        short8 a1a = *(const short8*)(wrelh + cm * 72 + q * 8);
        short8 a1b = *(const short8*)(wrelh + cm * 72 + 32 + q * 8);
        float4v d1 = {0.f, 0.f, 0.f, 0.f};
        d1 = __builtin_amdgcn_mfma_f32_16x16x32_bf16(a1a, bf1a, d1, 0, 0, 0);
        d1 = __builtin_amdgcn_mfma_f32_16x16x32_bf16(a1b, bf1b, d1, 0, 0, 0);
#pragma unroll
        for (int r = 0; r < 4; ++r) {
            float hv = fmaxf(fmaf(d1[r] + bw1c, s2c, o2c), 0.f);
            if (colv) hLh[(q * 4 + r) * 40 + cm] = f2bfF(hv);
        }
        CBAR();

        // ---- Phase B2 (MFMA, K=8 zero-padded): h @ Ww2^T -> logits ----
        short8 a2 = *(const short8*)(hLh + cm * 40 + q * 8);
        float4v d2 = {0.f, 0.f, 0.f, 0.f};
        d2 = __builtin_amdgcn_mfma_f32_16x16x32_bf16(a2, bf2, d2, 0, 0, 0);

        // ---- Phase C: softmax over j, no max-sub (logits bounded) ----
        float e0 = __expf(d2[0]), e1 = __expf(d2[1]);
        float e2 = __expf(d2[2]), e3 = __expf(d2[3]);
        float ss = (e0 + e1) + (e2 + e3);
        ss += __shfl_xor(ss, 16);
        ss += __shfl_xor(ss, 32);
        float inv = 1.f / ss;
        if (colv) {
            *(float4*)(wgt + cm * 20 + q * 4) =
                make_float4(e0 * inv, e1 * inv, e2 * inv, e3 * inv);
        }
        CBAR();

        // ---- weighted sum over neighbors (4 b128 broadcast reads) ----
        float acc = 0.f;
#pragma unroll
        for (int gq = 0; gq < 4; ++gq) {
            float4 wv4 = *(const float4*)(wgt + m8 * 20 + gq * 4);
            acc = fmaf(wv4.x, vpe[gq * 4 + 0], acc);
            acc = fmaf(wv4.y, vpe[gq * 4 + 1], acc);
            acc = fmaf(wv4.z, vpe[gq * 4 + 2], acc);
            acc = fmaf(wv4.w, vpe[gq * 4 + 3], acc);
        }
        CBAR();
        out[(size_t)(nbase + pt) * 64 + lane] = acc;
    };

    // 2-deep pipelined strip
    computeF(0, ga);
    issueF(2, ga);
    computeF(1, gb);
    issueF(3, gb);
    computeF(2, ga);
    computeF(3, gb);
}

extern "C" void kernel_launch(void* const* d_in, const int* in_sizes, int n_in,
                              void* d_out, int out_size, void* d_ws, size_t ws_size,
                              hipStream_t stream) {
    const float* p   = (const float*)d_in[0];
    const float* x   = (const float*)d_in[1];
    const int*   idx = (const int*)d_in[2];
    const float* Wq  = (const float*)d_in[3];  const float* bq  = (const float*)d_in[4];
    const float* Wk  = (const float*)d_in[5];  const float* bk  = (const float*)d_in[6];
    const float* Wv  = (const float*)d_in[7];  const float* bv  = (const float*)d_in[8];
    const float* Wp1 = (const float*)d_in[9];  const float* bp1 = (const float*)d_in[10];
    const float* pg  = (const float*)d_in[11]; const float* pb  = (const float*)d_in[12];
    const float* pm  = (const float*)d_in[13]; const float* pv  = (const float*)d_in[14];
    const float* Wp2 = (const float*)d_in[15]; const float* bp2 = (const float*)d_in[16];
    const float* wg1 = (const float*)d_in[17]; const float* wb1 = (const float*)d_in[18];
    const float* wm1 = (const float*)d_in[19]; const float* wv1 = (const float*)d_in[20];
    const float* Ww1 = (const float*)d_in[21]; const float* bw1 = (const float*)d_in[22];
    const float* wg2 = (const float*)d_in[23]; const float* wb2 = (const float*)d_in[24];
    const float* wm2 = (const float*)d_in[25]; const float* wv2 = (const float*)d_in[26];
    const float* Ww2 = (const float*)d_in[27]; const float* bw2 = (const float*)d_in[28];

    float*  xqw = (float*)d_ws;
    uint_t* kvw = (uint_t*)((char*)d_ws + (size_t)NPTS * 64 * sizeof(float));
    float*  outp = (float*)d_out;

    k_qkv<<<dim3(NPTS / 64), dim3(256), 0, stream>>>(x, Wq, bq, Wk, bk, Wv, bv, xqw, kvw);
    k_attn<<<dim3(NPTS / 16), dim3(256), 0, stream>>>(p, idx, xqw, kvw,
                                                      Wp1, bp1, pg, pb, pm, pv, Wp2, bp2,
                                                      wg1, wb1, wm1, wv1, Ww1, bw1,
                                                      wg2, wb2, wm2, wv2, Ww2, bw2, outp);
}